// Round 1
// 218.471 us; speedup vs baseline: 1.0158x; 1.0158x over previous
//
#include <hip/hip_runtime.h>
#include <hip/hip_bf16.h>
#include <stdint.h>

// ---------------------------------------------------------------------------
// O = softmax(q_n . k_n^T) @ keys_raw   (N=65536, K=4096, D=128)
// 32x32x16 MFMA, transposed scheme: S^T = Kn.Qn^T, O^T = V^T.P^T; pi folded
// into vtf packing so S^T output regs ARE the PV B-fragment after exp+pack.
// R6: deepen the cross-iteration pipeline. exp is shifted one full iteration
// later (S ping-pong Sa/Sb, loop unrolled x2 for static indexing) so each
// sub-iter runs {computeS(cur) MFMA chain} || {doExp(prev) VALU} || {doPV}.
// This removes the per-iter pure-VALU exp tail that serialized after the
// S-chain. V-tile chunk 0 loads are issued right after stage() (T14
// issue-early) so L2 latency hides under computeS+doExp. s_setprio(1) wraps
// the MFMA-dense region (T5; 2 waves/SIMD come from independent blocks).
//   knf blob: chunk c = blk64*1024 + t*512 + ds*64 + lane  (16B chunks, LDS)
//   vtf blob: chunk c = blk64*1024 + s*256 + db2*64 + lane (direct L2)
// ---------------------------------------------------------------------------

typedef __attribute__((ext_vector_type(8))) short bf16x8;
typedef __attribute__((ext_vector_type(16))) float f32x16;

#define MFMA32(a, b, c) __builtin_amdgcn_mfma_f32_32x32x16_bf16(a, b, c, 0, 0, 0)
#define ASYNC_CP16(gsrc, ldst)                                                  \
  __builtin_amdgcn_global_load_lds(                                             \
      (const __attribute__((address_space(1))) void*)(gsrc),                    \
      (__attribute__((address_space(3))) void*)(ldst), 16, 0, 0)

__device__ __forceinline__ unsigned pkbf(float lo, float hi) {
  union { __hip_bfloat162 h2; unsigned u; } v;
  v.h2 = __float22bfloat162_rn(float2{lo, hi});
  return v.u;
}

// ---------------- prep_k: fragment-pack Kn (normalized) and V^T (raw) -------
__global__ __launch_bounds__(256) void prep_k(const float* __restrict__ k,
                                              char* __restrict__ knf,
                                              char* __restrict__ vtf, int K) {
  __shared__ float sRaw[64 * 132];
  __shared__ float sScale[64];
  const int tid = threadIdx.x;
  const int kbase = blockIdx.x * 64;
  {
    const int key_loc = tid >> 2, dq = tid & 3;
    const float4* src = (const float4*)(k + (size_t)(kbase + key_loc) * 128 + dq * 32);
    float4 f[8];
    float ss = 0.f;
#pragma unroll
    for (int i = 0; i < 8; ++i) {
      f[i] = src[i];
      ss += f[i].x * f[i].x + f[i].y * f[i].y + f[i].z * f[i].z + f[i].w * f[i].w;
    }
    ss += __shfl_xor(ss, 1);
    ss += __shfl_xor(ss, 2);
    float4* dst = (float4*)(sRaw + key_loc * 132 + dq * 32);
#pragma unroll
    for (int i = 0; i < 8; ++i) dst[i] = f[i];
    if (dq == 0) sScale[key_loc] = ss > 0.f ? rsqrtf(ss) : 0.f;
  }
  __syncthreads();

  // knf: 1024 chunks of 16B per 64-key block
#pragma unroll
  for (int r = 0; r < 4; ++r) {
    const int c = r * 256 + tid;
    const int t_loc = c >> 9, ds = (c >> 6) & 7, l = c & 63;
    const int h5 = l >> 5, c32 = l & 31;
    const int key_loc = t_loc * 32 + c32;
    const float sc = sScale[key_loc];
    const float* p = sRaw + key_loc * 132 + ds * 16 + h5 * 8;
    uint4 w;
    w.x = pkbf(p[0] * sc, p[1] * sc);
    w.y = pkbf(p[2] * sc, p[3] * sc);
    w.z = pkbf(p[4] * sc, p[5] * sc);
    w.w = pkbf(p[6] * sc, p[7] * sc);
    *(uint4*)(knf + ((size_t)blockIdx.x * 1024 + c) * 16) = w;
  }
  // vtf: 1024 chunks; pi(s,h5,j) = (s>>1)*32 + (s&1)*8 + h5*4 + (j&3) + 16*(j>>2)
#pragma unroll
  for (int r = 0; r < 4; ++r) {
    const int c = r * 256 + tid;
    const int s = c >> 8, db2 = (c >> 6) & 3, l = c & 63;
    const int h5 = l >> 5, c32 = l & 31;
    const int d = db2 * 32 + c32;
    const int kb = (s >> 1) * 32 + (s & 1) * 8 + h5 * 4;
    float f[8];
#pragma unroll
    for (int j = 0; j < 8; ++j)
      f[j] = sRaw[(kb + (j & 3) + (j >> 2) * 16) * 132 + d];
    uint4 w;
    w.x = pkbf(f[0], f[1]);
    w.y = pkbf(f[2], f[3]);
    w.z = pkbf(f[4], f[5]);
    w.w = pkbf(f[6], f[7]);
    *(uint4*)(vtf + ((size_t)blockIdx.x * 1024 + c) * 16) = w;
  }
}

// ----------------------------- fused attention ------------------------------
// 256 thr = 4 waves x 32 q-rows; grid N/128 = 512.
__global__ __launch_bounds__(256, 2) void attn_main(
    const float* __restrict__ q, const char* __restrict__ knf,
    const char* __restrict__ vtf, float* __restrict__ out, int K) {
  __shared__ __align__(16) char sK[2][16384];
  const int tid = threadIdx.x;
  const int wave = tid >> 6, lane = tid & 63;
  const int h5 = lane >> 5, c32 = lane & 31;
  const int qrow0 = blockIdx.x * 128 + wave * 32;

  // ---- Q: load row (qrow0+c32), normalize, fold log2e, pack B-fragments ---
  bf16x8 qf[8];
  {
    const float* qr = q + (size_t)(qrow0 + c32) * 128;
    float f[64];
    float ss = 0.f;
#pragma unroll
    for (int ds = 0; ds < 8; ++ds) {
      const float4 a = *(const float4*)(qr + ds * 16 + h5 * 8);
      const float4 b = *(const float4*)(qr + ds * 16 + h5 * 8 + 4);
      f[ds * 8 + 0] = a.x; f[ds * 8 + 1] = a.y; f[ds * 8 + 2] = a.z; f[ds * 8 + 3] = a.w;
      f[ds * 8 + 4] = b.x; f[ds * 8 + 5] = b.y; f[ds * 8 + 6] = b.z; f[ds * 8 + 7] = b.w;
    }
#pragma unroll
    for (int i = 0; i < 64; ++i) ss += f[i] * f[i];
    ss += __shfl_xor(ss, 32);
    const float sc = (ss > 0.f ? rsqrtf(ss) : 0.f) * 1.44269504f;
#pragma unroll
    for (int ds = 0; ds < 8; ++ds) {
      union { unsigned u[4]; bf16x8 v; } t;
#pragma unroll
      for (int p = 0; p < 4; ++p)
        t.u[p] = pkbf(f[ds * 8 + 2 * p] * sc, f[ds * 8 + 2 * p + 1] * sc);
      qf[ds] = t.v;
    }
  }

  f32x16 acc[4];
#pragma unroll
  for (int db2 = 0; db2 < 4; ++db2)
#pragma unroll
    for (int r = 0; r < 16; ++r) acc[db2][r] = 0.f;
  float den = 0.f;
  f32x16 Zf;
#pragma unroll
  for (int r = 0; r < 16; ++r) Zf[r] = 0.f;

  union pfu { unsigned u[4]; bf16x8 v; };
  pfu pf[4];          // P fragments (B-frags for PV), refreshed each sub-iter
  f32x16 Sa[2], Sb[2];  // S ping-pong: even tiles -> Sa, odd tiles -> Sb
  bf16x8 vcur[4];       // early-issued V chunk-0 block of the PV tile

  const int nIter = K >> 6;   // 64 iters of 64 keys (assumed even, >= 4)

  auto stage = [&](int it, int buf) {
#pragma unroll
    for (int i = 0; i < 4; ++i)
      ASYNC_CP16(knf + (size_t)it * 16384 + (wave * 4 + i) * 1024 + lane * 16,
                 sK[buf] + (wave * 4 + i) * 1024);
  };

  // S^T = Kn . Qn^T for tile in sK[buf] (2 independent chains of 8)
  auto computeS = [&](int buf, f32x16* S) {
#pragma unroll
    for (int t = 0; t < 2; ++t) {
      f32x16 s;
#pragma unroll
      for (int ds = 0; ds < 8; ++ds) {
        const bf16x8 kf = *(const bf16x8*)(sK[buf] + (t * 8 + ds) * 1024 + lane * 16);
        s = MFMA32(kf, qf[ds], (ds == 0) ? Zf : s);
      }
      S[t] = s;
    }
  };

  // exp(S_prev) -> pf (B-fragments for this sub-iter's PV), den accumulate.
  // Independent of the S currently being built -> co-issues with MFMA chain.
  auto doExp = [&](const f32x16* S) {
#pragma unroll
    for (int s = 0; s < 4; ++s) {
      const int t = s >> 1, w = s & 1;
      float e[8];
#pragma unroll
      for (int j = 0; j < 8; ++j) {
        const int rr = w * 4 + (j & 3) + (j >> 2) * 8;
        e[j] = __builtin_amdgcn_exp2f(S[t][rr]);
      }
      den += ((e[0] + e[1]) + (e[2] + e[3])) + ((e[4] + e[5]) + (e[6] + e[7]));
#pragma unroll
      for (int j2 = 0; j2 < 4; ++j2) pf[s].u[j2] = pkbf(e[2 * j2], e[2 * j2 + 1]);
    }
  };

  // early-issue the first 4 V chunks of PV tile m (T14: L2 latency hides
  // under computeS+doExp before doPV consumes them)
  auto loadV0 = [&](int m) {
    const char* vbase = vtf + (size_t)m * 16384;
#pragma unroll
    for (int db2 = 0; db2 < 4; ++db2)
      vcur[db2] = *(const bf16x8*)(vbase + db2 * 1024 + lane * 16);
  };

  // PV for tile m using pf[] (16 MFMAs in 4 independent chains); vcur holds
  // the s=0 chunks already in flight, remaining chunks roll s+1 ahead.
  auto doPV = [&](int m) {
    const char* vbase = vtf + (size_t)m * 16384;
    bf16x8 vnxt[4];
#pragma unroll
    for (int s = 0; s < 4; ++s) {
      if (s < 3)
#pragma unroll
        for (int db2 = 0; db2 < 4; ++db2)
          vnxt[db2] = *(const bf16x8*)(vbase + ((s + 1) * 4 + db2) * 1024 + lane * 16);
#pragma unroll
      for (int db2 = 0; db2 < 4; ++db2)
        acc[db2] = MFMA32(vcur[db2], pf[s].v, acc[db2]);
      if (s < 3)
#pragma unroll
        for (int db2 = 0; db2 < 4; ++db2) vcur[db2] = vnxt[db2];
    }
  };

  // ---- pipelined K-loop ----------------------------------------------------
  // sub-iter it: {sync; stage(it+1); loadV0(it-1); S(it) || exp(S(it-1)); PV(it-1)}
  stage(0, 0);
  __syncthreads();            // tile 0 landed
  stage(1, 1);
  computeS(0, Sa);            // S(0)

  // sub-iter 1 (peeled):
  __syncthreads();            // tile 1 landed; tile-0 ds_reads drained
  stage(2, 0);
  loadV0(0);
  __builtin_amdgcn_s_setprio(1);
  computeS(1, Sb);            // S(1)
  doExp(Sa);                  // pf <- exp(S(0))  (independent VALU stream)
  doPV(0);
  __builtin_amdgcn_s_setprio(0);

  for (int itp = 2; itp < nIter; itp += 2) {
    // ---- even sub-iter itp: cur -> Sa, prev = Sb, PV(itp-1) ----
    __syncthreads();          // tile itp landed; old buf0 reads drained
    stage(itp + 1, 1);
    loadV0(itp - 1);
    __builtin_amdgcn_s_setprio(1);
    computeS(0, Sa);
    doExp(Sb);                // pf <- exp(S(itp-1))
    doPV(itp - 1);
    __builtin_amdgcn_s_setprio(0);

    // ---- odd sub-iter itp+1: cur -> Sb, prev = Sa, PV(itp) ----
    __syncthreads();          // tile itp+1 landed; old buf1 reads drained
    if (itp + 2 < nIter) stage(itp + 2, 0);
    loadV0(itp);
    __builtin_amdgcn_s_setprio(1);
    computeS(1, Sb);
    doExp(Sa);                // pf <- exp(S(itp))
    doPV(itp);
    __builtin_amdgcn_s_setprio(0);
  }

  // drain: exp + PV of the last tile (vtf from L2, no barrier needed)
  loadV0(nIter - 1);
  doExp(Sb);                  // pf <- exp(S(nIter-1))
  doPV(nIter - 1);

  den += __shfl_xor(den, 32);
  const float rd = 1.0f / den;

  // ---- epilogue: per-wave LDS transpose (XOR-swizzled), coalesced stores ---
  __syncthreads();            // all waves done with sK
  float* wls = (float*)(&sK[0][0] + wave * 4096);   // 32 q-rows x 32 floats
#pragma unroll
  for (int db2 = 0; db2 < 4; ++db2) {
#pragma unroll
    for (int qd = 0; qd < 4; ++qd) {
      float4 v;
      v.x = acc[db2][qd * 4 + 0] * rd;
      v.y = acc[db2][qd * 4 + 1] * rd;
      v.z = acc[db2][qd * 4 + 2] * rd;
      v.w = acc[db2][qd * 4 + 3] * rd;
      *(float4*)(wls + c32 * 32 + (((h5 + 2 * qd) ^ (c32 & 7)) << 2)) = v;
    }
#pragma unroll
    for (int p = 0; p < 4; ++p) {
      const int ql = p * 8 + (lane >> 3);
      const int x = lane & 7;
      const float4 v = *(const float4*)(wls + ql * 32 + ((x ^ (ql & 7)) << 2));
      *(float4*)(out + (size_t)(qrow0 + ql) * 128 + db2 * 32 + x * 4) = v;
    }
  }
}

// ---------------------------------------------------------------------------
extern "C" void kernel_launch(void* const* d_in, const int* in_sizes, int n_in,
                              void* d_out, int out_size, void* d_ws, size_t ws_size,
                              hipStream_t stream) {
  const float* q = (const float*)d_in[0];
  const float* k = (const float*)d_in[1];
  const int N = in_sizes[0] / 128;   // 65536
  const int K = in_sizes[1] / 128;   // 4096
  char* ws = (char*)d_ws;
  char* knf = ws;                          // K*256 B = 1 MB
  char* vtf = ws + (size_t)K * 256;        // 1 MB
  float* out = (float*)d_out;

  prep_k<<<dim3(K / 64), dim3(256), 0, stream>>>(k, knf, vtf, K);
  attn_main<<<dim3(N / 128), dim3(256), 0, stream>>>(q, knf, vtf, out, K);
}

// Round 3
// 202.273 us; speedup vs baseline: 1.0971x; 1.0801x over previous
//
#include <hip/hip_runtime.h>
#include <hip/hip_bf16.h>
#include <stdint.h>

// ---------------------------------------------------------------------------
// O = softmax(q_n . k_n^T) @ keys_raw   (N=65536, K=4096, D=128)
// 32x32x16 MFMA, transposed scheme: S^T = Kn.Qn^T, O^T = V^T.P^T; pi folded
// into vtf packing so S^T output regs ARE the PV B-fragment after exp+pack.
// R7 (resubmit; previous round died on container acquire, not the kernel):
// V goes through LDS. Previously doPV streamed the 16KB V-tile from L2 into
// VGPRs per wave (4x re-read per block, ~200cy L2 latency only ~128cy covered
// by the rolling prefetch, plus 64-bit addr arith per load). Now V is staged
// once per block via global_load_lds into a double-buffered sV and read with
// ds_read_b128 at uniform-base + 16-bit imm offsets. V is consumed one tile
// behind K (PV lags one iter), so iteration it stages V(it) into sV[it&1] --
// write target's last reader drained at the preceding barrier.
// Keeps R6's exp-shift pipeline (S ping-pong Sa/Sb) and setprio(1) region.
//   knf blob: chunk c = blk64*1024 + t*512 + ds*64 + lane  (16B chunks)
//   vtf blob: chunk c = blk64*1024 + s*256 + db2*64 + lane (16B chunks)
// ---------------------------------------------------------------------------

typedef __attribute__((ext_vector_type(8))) short bf16x8;
typedef __attribute__((ext_vector_type(16))) float f32x16;

#define MFMA32(a, b, c) __builtin_amdgcn_mfma_f32_32x32x16_bf16(a, b, c, 0, 0, 0)
#define ASYNC_CP16(gsrc, ldst)                                                  \
  __builtin_amdgcn_global_load_lds(                                             \
      (const __attribute__((address_space(1))) void*)(gsrc),                    \
      (__attribute__((address_space(3))) void*)(ldst), 16, 0, 0)

__device__ __forceinline__ unsigned pkbf(float lo, float hi) {
  union { __hip_bfloat162 h2; unsigned u; } v;
  v.h2 = __float22bfloat162_rn(float2{lo, hi});
  return v.u;
}

// ---------------- prep_k: fragment-pack Kn (normalized) and V^T (raw) -------
__global__ __launch_bounds__(256) void prep_k(const float* __restrict__ k,
                                              char* __restrict__ knf,
                                              char* __restrict__ vtf, int K) {
  __shared__ float sRaw[64 * 132];
  __shared__ float sScale[64];
  const int tid = threadIdx.x;
  const int kbase = blockIdx.x * 64;
  {
    const int key_loc = tid >> 2, dq = tid & 3;
    const float4* src = (const float4*)(k + (size_t)(kbase + key_loc) * 128 + dq * 32);
    float4 f[8];
    float ss = 0.f;
#pragma unroll
    for (int i = 0; i < 8; ++i) {
      f[i] = src[i];
      ss += f[i].x * f[i].x + f[i].y * f[i].y + f[i].z * f[i].z + f[i].w * f[i].w;
    }
    ss += __shfl_xor(ss, 1);
    ss += __shfl_xor(ss, 2);
    float4* dst = (float4*)(sRaw + key_loc * 132 + dq * 32);
#pragma unroll
    for (int i = 0; i < 8; ++i) dst[i] = f[i];
    if (dq == 0) sScale[key_loc] = ss > 0.f ? rsqrtf(ss) : 0.f;
  }
  __syncthreads();

  // knf: 1024 chunks of 16B per 64-key block
#pragma unroll
  for (int r = 0; r < 4; ++r) {
    const int c = r * 256 + tid;
    const int t_loc = c >> 9, ds = (c >> 6) & 7, l = c & 63;
    const int h5 = l >> 5, c32 = l & 31;
    const int key_loc = t_loc * 32 + c32;
    const float sc = sScale[key_loc];
    const float* p = sRaw + key_loc * 132 + ds * 16 + h5 * 8;
    uint4 w;
    w.x = pkbf(p[0] * sc, p[1] * sc);
    w.y = pkbf(p[2] * sc, p[3] * sc);
    w.z = pkbf(p[4] * sc, p[5] * sc);
    w.w = pkbf(p[6] * sc, p[7] * sc);
    *(uint4*)(knf + ((size_t)blockIdx.x * 1024 + c) * 16) = w;
  }
  // vtf: 1024 chunks; pi(s,h5,j) = (s>>1)*32 + (s&1)*8 + h5*4 + (j&3) + 16*(j>>2)
#pragma unroll
  for (int r = 0; r < 4; ++r) {
    const int c = r * 256 + tid;
    const int s = c >> 8, db2 = (c >> 6) & 3, l = c & 63;
    const int h5 = l >> 5, c32 = l & 31;
    const int d = db2 * 32 + c32;
    const int kb = (s >> 1) * 32 + (s & 1) * 8 + h5 * 4;
    float f[8];
#pragma unroll
    for (int j = 0; j < 8; ++j)
      f[j] = sRaw[(kb + (j & 3) + (j >> 2) * 16) * 132 + d];
    uint4 w;
    w.x = pkbf(f[0], f[1]);
    w.y = pkbf(f[2], f[3]);
    w.z = pkbf(f[4], f[5]);
    w.w = pkbf(f[6], f[7]);
    *(uint4*)(vtf + ((size_t)blockIdx.x * 1024 + c) * 16) = w;
  }
}

// ----------------------------- fused attention ------------------------------
// 256 thr = 4 waves x 32 q-rows; grid N/128 = 512. LDS 64KB: 2 blocks/CU.
__global__ __launch_bounds__(256, 2) void attn_main(
    const float* __restrict__ q, const char* __restrict__ knf,
    const char* __restrict__ vtf, float* __restrict__ out, int K) {
  __shared__ __align__(16) char sK[2][16384];
  __shared__ __align__(16) char sV[2][16384];
  const int tid = threadIdx.x;
  const int wave = tid >> 6, lane = tid & 63;
  const int h5 = lane >> 5, c32 = lane & 31;
  const int qrow0 = blockIdx.x * 128 + wave * 32;

  // ---- Q: load row (qrow0+c32), normalize, fold log2e, pack B-fragments ---
  bf16x8 qf[8];
  {
    const float* qr = q + (size_t)(qrow0 + c32) * 128;
    float f[64];
    float ss = 0.f;
#pragma unroll
    for (int ds = 0; ds < 8; ++ds) {
      const float4 a = *(const float4*)(qr + ds * 16 + h5 * 8);
      const float4 b = *(const float4*)(qr + ds * 16 + h5 * 8 + 4);
      f[ds * 8 + 0] = a.x; f[ds * 8 + 1] = a.y; f[ds * 8 + 2] = a.z; f[ds * 8 + 3] = a.w;
      f[ds * 8 + 4] = b.x; f[ds * 8 + 5] = b.y; f[ds * 8 + 6] = b.z; f[ds * 8 + 7] = b.w;
    }
#pragma unroll
    for (int i = 0; i < 64; ++i) ss += f[i] * f[i];
    ss += __shfl_xor(ss, 32);
    const float sc = (ss > 0.f ? rsqrtf(ss) : 0.f) * 1.44269504f;
#pragma unroll
    for (int ds = 0; ds < 8; ++ds) {
      union { unsigned u[4]; bf16x8 v; } t;
#pragma unroll
      for (int p = 0; p < 4; ++p)
        t.u[p] = pkbf(f[ds * 8 + 2 * p] * sc, f[ds * 8 + 2 * p + 1] * sc);
      qf[ds] = t.v;
    }
  }

  f32x16 acc[4];
#pragma unroll
  for (int db2 = 0; db2 < 4; ++db2)
#pragma unroll
    for (int r = 0; r < 16; ++r) acc[db2][r] = 0.f;
  float den = 0.f;
  f32x16 Zf;
#pragma unroll
  for (int r = 0; r < 16; ++r) Zf[r] = 0.f;

  union pfu { unsigned u[4]; bf16x8 v; };
  pfu pf[4];            // P fragments (B-frags for PV), refreshed each sub-iter
  f32x16 Sa[2], Sb[2];  // S ping-pong: even tiles -> Sa, odd tiles -> Sb

  const int nIter = K >> 6;   // 64 iters of 64 keys (even, >= 4)

  auto stageK = [&](int it, int buf) {
#pragma unroll
    for (int i = 0; i < 4; ++i)
      ASYNC_CP16(knf + (size_t)it * 16384 + (wave * 4 + i) * 1024 + lane * 16,
                 sK[buf] + (wave * 4 + i) * 1024);
  };
  auto stageV = [&](int it, int buf) {
#pragma unroll
    for (int i = 0; i < 4; ++i)
      ASYNC_CP16(vtf + (size_t)it * 16384 + (wave * 4 + i) * 1024 + lane * 16,
                 sV[buf] + (wave * 4 + i) * 1024);
  };

  // S^T = Kn . Qn^T for tile in sK[buf] (2 independent chains of 8)
  auto computeS = [&](int buf, f32x16* S) {
#pragma unroll
    for (int t = 0; t < 2; ++t) {
      f32x16 s;
#pragma unroll
      for (int ds = 0; ds < 8; ++ds) {
        const bf16x8 kf = *(const bf16x8*)(sK[buf] + (t * 8 + ds) * 1024 + lane * 16);
        s = MFMA32(kf, qf[ds], (ds == 0) ? Zf : s);
      }
      S[t] = s;
    }
  };

  // exp(S_prev) -> pf (B-fragments for this sub-iter's PV), den accumulate.
  // Independent of the S currently being built -> co-issues with MFMA chain.
  auto doExp = [&](const f32x16* S) {
#pragma unroll
    for (int s = 0; s < 4; ++s) {
      const int t = s >> 1, w = s & 1;
      float e[8];
#pragma unroll
      for (int j = 0; j < 8; ++j) {
        const int rr = w * 4 + (j & 3) + (j >> 2) * 8;
        e[j] = __builtin_amdgcn_exp2f(S[t][rr]);
      }
      den += ((e[0] + e[1]) + (e[2] + e[3])) + ((e[4] + e[5]) + (e[6] + e[7]));
#pragma unroll
      for (int j2 = 0; j2 < 4; ++j2) pf[s].u[j2] = pkbf(e[2 * j2], e[2 * j2 + 1]);
    }
  };

  // PV from LDS: 16 ds_read_b128 at uniform base + imm offsets, 16 MFMAs in
  // 4 independent acc chains. Compiler interleaves reads/MFMAs (lgkmcnt).
  auto doPV = [&](int buf) {
    const char* vb = sV[buf] + lane * 16;
#pragma unroll
    for (int s = 0; s < 4; ++s) {
      bf16x8 v0 = *(const bf16x8*)(vb + (s * 4 + 0) * 1024);
      bf16x8 v1 = *(const bf16x8*)(vb + (s * 4 + 1) * 1024);
      bf16x8 v2 = *(const bf16x8*)(vb + (s * 4 + 2) * 1024);
      bf16x8 v3 = *(const bf16x8*)(vb + (s * 4 + 3) * 1024);
      acc[0] = MFMA32(v0, pf[s].v, acc[0]);
      acc[1] = MFMA32(v1, pf[s].v, acc[1]);
      acc[2] = MFMA32(v2, pf[s].v, acc[2]);
      acc[3] = MFMA32(v3, pf[s].v, acc[3]);
    }
  };

  // ---- pipelined K-loop ----------------------------------------------------
  // iter it: {sync; stageK(it+1); stageV(it); S(it) || exp(S(it-1)); PV(it-1)}
  // V(it) lands by the barrier of iter it+1, exactly when PV(it) needs it.
  stageK(0, 0);
  stageV(0, 0);
  __syncthreads();            // K0, V0 landed
  stageK(1, 1);
  computeS(0, Sa);            // S(0)

  // iter 1 (peeled):
  __syncthreads();            // K1 landed; tile-0 ds_reads drained
  stageK(2, 0);
  stageV(1, 1);
  __builtin_amdgcn_s_setprio(1);
  computeS(1, Sb);            // S(1)
  doExp(Sa);                  // pf <- exp(S(0))
  doPV(0);                    // V(0) from sV[0]
  __builtin_amdgcn_s_setprio(0);

  for (int itp = 2; itp < nIter; itp += 2) {
    // ---- even iter itp: cur -> Sa, prev = Sb, PV(itp-1) from sV[1] ----
    __syncthreads();          // K(itp), V(itp-1) landed; old reads drained
    stageK(itp + 1, 1);
    stageV(itp, 0);
    __builtin_amdgcn_s_setprio(1);
    computeS(0, Sa);
    doExp(Sb);                // pf <- exp(S(itp-1))
    doPV(1);
    __builtin_amdgcn_s_setprio(0);

    // ---- odd iter itp+1: cur -> Sb, prev = Sa, PV(itp) from sV[0] ----
    __syncthreads();          // K(itp+1), V(itp) landed
    if (itp + 2 < nIter) stageK(itp + 2, 0);
    stageV(itp + 1, 1);
    __builtin_amdgcn_s_setprio(1);
    computeS(1, Sb);
    doExp(Sa);                // pf <- exp(S(itp))
    doPV(0);
    __builtin_amdgcn_s_setprio(0);
  }

  // drain: V(nIter-1) was staged at iter nIter-1; barrier to land it.
  __syncthreads();
  doExp(Sb);                  // pf <- exp(S(nIter-1))
  doPV(1);                    // (nIter-1) odd -> sV[1]

  den += __shfl_xor(den, 32);
  const float rd = 1.0f / den;

  // ---- epilogue: per-wave LDS transpose (XOR-swizzled), coalesced stores ---
  __syncthreads();            // all waves done with sK/sV
  float* wls = (float*)(&sK[0][0] + wave * 4096);   // 32 q-rows x 32 floats
#pragma unroll
  for (int db2 = 0; db2 < 4; ++db2) {
#pragma unroll
    for (int qd = 0; qd < 4; ++qd) {
      float4 v;
      v.x = acc[db2][qd * 4 + 0] * rd;
      v.y = acc[db2][qd * 4 + 1] * rd;
      v.z = acc[db2][qd * 4 + 2] * rd;
      v.w = acc[db2][qd * 4 + 3] * rd;
      *(float4*)(wls + c32 * 32 + (((h5 + 2 * qd) ^ (c32 & 7)) << 2)) = v;
    }
#pragma unroll
    for (int p = 0; p < 4; ++p) {
      const int ql = p * 8 + (lane >> 3);
      const int x = lane & 7;
      const float4 v = *(const float4*)(wls + ql * 32 + ((x ^ (ql & 7)) << 2));
      *(float4*)(out + (size_t)(qrow0 + ql) * 128 + db2 * 32 + x * 4) = v;
    }
  }
}

// ---------------------------------------------------------------------------
extern "C" void kernel_launch(void* const* d_in, const int* in_sizes, int n_in,
                              void* d_out, int out_size, void* d_ws, size_t ws_size,
                              hipStream_t stream) {
  const float* q = (const float*)d_in[0];
  const float* k = (const float*)d_in[1];
  const int N = in_sizes[0] / 128;   // 65536
  const int K = in_sizes[1] / 128;   // 4096
  char* ws = (char*)d_ws;
  char* knf = ws;                          // K*256 B = 1 MB
  char* vtf = ws + (size_t)K * 256;        // 1 MB
  float* out = (float*)d_out;

  prep_k<<<dim3(K / 64), dim3(256), 0, stream>>>(k, knf, vtf, K);
  attn_main<<<dim3(N / 128), dim3(256), 0, stream>>>(q, knf, vtf, out, K);
}